// Round 4
// baseline (9496.512 us; speedup 1.0000x reference)
//
#include <hip/hip_runtime.h>

// ---------------------------------------------------------------------------
// TorchAttractorLanguageModel. Round 3 finding: scan was LDS-return-BW bound
// (uniform ds_read broadcast of s costs full 1KB/instr return; 1.5MB/step =
// 18Kcy = the measured stall). Round 4: wave-k-split GEMM — wave w owns k in
// [64w,64w+64), lane l produces partials for j=l+64*i; s read as tiny uniform
// slices (16KB/wave/step); partials reduced via pad-516 LDS (conflict-free).
// B=128 blocks x RR=2 rows. k_logits rewritten with 8x8 register tiles.
// ---------------------------------------------------------------------------

static constexpr int   kB     = 256;
static constexpr int   kT     = 32;
static constexpr int   kV     = 50257;
static constexpr int   kD     = 512;
static constexpr int   kSteps = 30;
static constexpr float kDT    = 0.04f;
static constexpr float kCubic = 0.008f;
static constexpr float kEpsLN = 1e-5f;

static constexpr int RR          = 2;     // state rows per scan block
static constexpr int SCAN_BLOCKS = kB / RR;   // 128

typedef _Float16 half1;
typedef _Float16 half2v __attribute__((ext_vector_type(2)));
union HU { unsigned int u; half2v h; half1 s[2]; unsigned short us[2]; };

#if defined(__has_builtin)
#if __has_builtin(__builtin_amdgcn_fdot2)
#define HAS_FDOT2 1
#endif
#endif

__device__ __forceinline__ float dot2acc(unsigned int a, unsigned int b, float c) {
  HU ua; ua.u = a;
  HU ub; ub.u = b;
#ifdef HAS_FDOT2
  return __builtin_amdgcn_fdot2(ua.h, ub.h, c, false);
#else
  c = fmaf((float)ua.s[0], (float)ub.s[0], c);
  return fmaf((float)ua.s[1], (float)ub.s[1], c);
#endif
}

// ---------------------------------------------------------------------------
// K1: all_sigs[v] = L2normalize(LayerNorm(emb[v])); also asq[v] = ||sig_v||^2
// in closed form (scale^2 * D * var) — matches the reference's explicit sum
// to ~1e-7, irrelevant vs threshold.
__global__ __launch_bounds__(128)
void k_signals(const float* __restrict__ emb, float* __restrict__ sigs,
               float* __restrict__ asq) {
  const int row = blockIdx.x;
  const int tid = threadIdx.x;
  const float4 x = reinterpret_cast<const float4*>(emb + (size_t)row * kD)[tid];
  float s = x.x + x.y + x.z + x.w;
  float q = x.x * x.x + x.y * x.y + x.z * x.z + x.w * x.w;
#pragma unroll
  for (int o = 32; o > 0; o >>= 1) {
    s += __shfl_xor(s, o);
    q += __shfl_xor(q, o);
  }
  __shared__ float ls[2], lq[2];
  const int wid = tid >> 6;
  if ((tid & 63) == 0) { ls[wid] = s; lq[wid] = q; }
  __syncthreads();
  s = ls[0] + ls[1];
  q = lq[0] + lq[1];
  const float mu   = s * (1.0f / kD);
  const float var  = fmaxf(q * (1.0f / kD) - mu * mu, 0.0f);
  const float rstd = rsqrtf(var + kEpsLN);
  const float n     = rstd * sqrtf((float)kD * var);
  const float scale = rstd / fmaxf(n, 1e-12f);
  float4 y;
  y.x = (x.x - mu) * scale;
  y.y = (x.y - mu) * scale;
  y.z = (x.z - mu) * scale;
  y.w = (x.w - mu) * scale;
  reinterpret_cast<float4*>(sigs + (size_t)row * kD)[tid] = y;
  if (tid == 0) asq[row] = scale * scale * (float)kD * var;
}

// ---------------------------------------------------------------------------
// K2: pack W to f16 in the wave-k-split layout. uint4 index:
//   ((w*8 + p)*8 + i)*64 + l   holds W[j = l+64i][k = 64w+8p .. +8)
// so a wave's load of (p,i) is 64 consecutive uint4 = 1KB contiguous.
__global__ __launch_bounds__(256)
void k_wprep(const float* __restrict__ dif, unsigned int* __restrict__ w2) {
  const int d = blockIdx.x * 256 + threadIdx.x;   // dword index, 131072 total
  const int qq = d & 3;
  const int u4 = d >> 2;
  const int l = u4 & 63;
  const int i = (u4 >> 6) & 7;
  const int p = (u4 >> 9) & 7;
  const int w = u4 >> 12;
  const int j = l + 64 * i;
  const int k = 64 * w + 8 * p + 2 * qq;
  HU u;
  u.s[0] = (half1)dif[(size_t)j * kD + k];
  u.s[1] = (half1)dif[(size_t)j * kD + k + 1];
  w2[d] = u.u;
}

// ---------------------------------------------------------------------------
__device__ __forceinline__ void comp8(const uint4 (&wv)[8], uint4 sv0, uint4 sv1,
                                      float (&acc)[RR][8]) {
#pragma unroll
  for (int i = 0; i < 8; ++i) {
    float a0 = acc[0][i];
    a0 = dot2acc(wv[i].x, sv0.x, a0);
    a0 = dot2acc(wv[i].y, sv0.y, a0);
    a0 = dot2acc(wv[i].z, sv0.z, a0);
    a0 = dot2acc(wv[i].w, sv0.w, a0);
    acc[0][i] = a0;
    float a1 = acc[1][i];
    a1 = dot2acc(wv[i].x, sv1.x, a1);
    a1 = dot2acc(wv[i].y, sv1.y, a1);
    a1 = dot2acc(wv[i].z, sv1.z, a1);
    a1 = dot2acc(wv[i].w, sv1.w, a1);
    acc[1][i] = a1;
  }
}

// K3: the scan. Wave w = k-slice [64w,64w+64); lane l accumulates partial y
// for j=l+64i. Partials reduced through red2[r][w][j] (row stride 516 floats
// -> bank (w*4+t)%32, conflict-free). Thread t owns j=t for update/mean.
__global__ __launch_bounds__(512)
void k_scan(const int* __restrict__ ids, const float* __restrict__ sigs,
            const uint4* __restrict__ w2, float* __restrict__ state,
            float* __restrict__ ssq) {
  const int tid  = threadIdx.x;
  const int lane = tid & 63;
  const int w    = tid >> 6;           // wave id == k-slice id
  const int b0   = blockIdx.x * RR;

  __shared__ unsigned short s_h[RR][kD];   // f16 state (2 KB)
  __shared__ float red[RR][8];             // mean partials
  __shared__ float red2[RR][8][516];       // GEMM partials (33 KB, padded)

  float s_reg[RR], sig[RR];
#pragma unroll
  for (int r = 0; r < RR; ++r) {
    s_reg[r] = 0.0f;
    s_h[r][tid] = 0;
    if (lane == 0) red[r][w] = 0.0f;
  }

  const uint4* __restrict__ wp = w2 + (w << 12) + lane;
  uint4 wA[8], wB[8];
#pragma unroll
  for (int i = 0; i < 8; ++i) wA[i] = wp[(i << 6)];   // chunk 0 in flight

  __syncthreads();                       // prologue B1

  const uint4* sh0 = reinterpret_cast<const uint4*>(&s_h[0][0]);
  const uint4* sh1 = reinterpret_cast<const uint4*>(&s_h[1][0]);

  for (int t = 0; t < kT; ++t) {
#pragma unroll
    for (int r = 0; r < RR; ++r) {
      const int id = ids[(b0 + r) * kT + t];
      sig[r] = sigs[(size_t)id * kD + tid];
    }
    for (int step = 0; step < kSteps; ++step) {
      // --- mean of previous state (partials left in red before B1) ---
      float mean[RR];
#pragma unroll
      for (int r = 0; r < RR; ++r) {
        float m = 0.0f;
#pragma unroll
        for (int ww = 0; ww < 8; ++ww) m += red[r][ww];
        mean[r] = m * (1.0f / kD);
      }
      // --- wave-k-split GEMM, 8 chunks, 2-window prefetch ---
      float acc[RR][8];
#pragma unroll
      for (int r = 0; r < RR; ++r)
#pragma unroll
        for (int i = 0; i < 8; ++i) acc[r][i] = 0.0f;

#pragma unroll
      for (int ph = 0; ph < 4; ++ph) {
        const int pb = ph * 2 + 1, pn = (ph * 2 + 2) & 7;
#pragma unroll
        for (int i = 0; i < 8; ++i) wB[i] = wp[(pb << 9) + (i << 6)];
        {
          const uint4 sv0 = sh0[8 * w + ph * 2];
          const uint4 sv1 = sh1[8 * w + ph * 2];
          comp8(wA, sv0, sv1, acc);
        }
#pragma unroll
        for (int i = 0; i < 8; ++i) wA[i] = wp[(pn << 9) + (i << 6)];
        {
          const uint4 sv0 = sh0[8 * w + pb];
          const uint4 sv1 = sh1[8 * w + pb];
          comp8(wB, sv0, sv1, acc);
        }
      }
      // --- write partials (lanes consecutive -> conflict-free) ---
#pragma unroll
      for (int r = 0; r < RR; ++r)
#pragma unroll
        for (int i = 0; i < 8; ++i)
          red2[r][w][lane + (i << 6)] = acc[r][i];
      __syncthreads();                   // B2
      // --- reduce partials: thread t owns j=t ---
      float y[RR];
#pragma unroll
      for (int r = 0; r < RR; ++r) {
        float m = 0.0f;
#pragma unroll
        for (int ww = 0; ww < 8; ++ww) m += red2[r][ww][tid];
        y[r] = m;
      }
      // --- update + clip; stash f16 state + mean partials for next step ---
      float part[RR];
#pragma unroll
      for (int r = 0; r < RR; ++r) {
        const float cc    = s_reg[r] - mean[r];
        const float drift = y[r] + kCubic * cc * cc * cc + sig[r];
        float sn = fmaf(kDT, drift, s_reg[r]);
        sn = fminf(fmaxf(sn, -80.0f), 80.0f);
        s_reg[r] = sn;
        HU u; u.s[0] = (half1)sn; u.s[1] = (half1)0.0f;
        s_h[r][tid] = u.us[0];
        part[r] = sn;
      }
#pragma unroll
      for (int o = 32; o > 0; o >>= 1) {
#pragma unroll
        for (int r = 0; r < RR; ++r) part[r] += __shfl_xor(part[r], o);
      }
      if (lane == 0) {
#pragma unroll
        for (int r = 0; r < RR; ++r) red[r][w] = part[r];
      }
      __syncthreads();                   // B1
    }
  }

  // --- write state + per-row sum of squares ---
  float part[RR];
#pragma unroll
  for (int r = 0; r < RR; ++r) part[r] = s_reg[r] * s_reg[r];
#pragma unroll
  for (int o = 32; o > 0; o >>= 1) {
#pragma unroll
    for (int r = 0; r < RR; ++r) part[r] += __shfl_xor(part[r], o);
  }
  if (lane == 0) {
#pragma unroll
    for (int r = 0; r < RR; ++r) red[r][w] = part[r];
  }
#pragma unroll
  for (int r = 0; r < RR; ++r)
    state[(size_t)(b0 + r) * kD + tid] = s_reg[r];
  __syncthreads();
  if (tid < RR) {
    float m = 0.0f;
#pragma unroll
    for (int ww = 0; ww < 8; ++ww) m += red[tid][ww];
    ssq[b0 + tid] = m;
  }
}

// ---------------------------------------------------------------------------
// K4: logits = -sqrt(max(ssq_b + asq_v - 2*s.a, 0))/temp. 128b x 128v tile,
// 256 threads, 8x8 register micro-tile (1 FMA per LDS byte). K-transposed
// LDS tiles: stT[k][b], atT[k][v]. Thread (tx,ty): b=ty*8..+8,
// v in {tx*4..+4} u {64+tx*4..+4} (float4 groups, 2-way-max bank aliasing).
static constexpr int LB = 128, LV = 128, KK = 32;

__global__ __launch_bounds__(256)
void k_logits(const float* __restrict__ state, const float* __restrict__ ssq,
              const float* __restrict__ sigs, const float* __restrict__ asq,
              const float* __restrict__ traw, float* __restrict__ out) {
  const int tid = threadIdx.x;
  const int vb = blockIdx.x >> 1, bb = blockIdx.x & 1;
  const int v0 = vb * LV, b0 = bb * LB;
  __shared__ float stT[KK][LB];   // 16 KB
  __shared__ float atT[KK][LV];   // 16 KB
  const int tx = tid & 15;
  const int ty = tid >> 4;

  float acc[8][8];
#pragma unroll
  for (int bi = 0; bi < 8; ++bi)
#pragma unroll
    for (int vi = 0; vi < 8; ++vi) acc[bi][vi] = 0.0f;

  for (int kc = 0; kc < kD / KK; ++kc) {
    __syncthreads();
    // load tiles transposed: 4 float4 per thread each
#pragma unroll
    for (int it = 0; it < 4; ++it) {
      const int idx = tid + it * 256;          // 0..1023
      const int bl = idx & 127, qc = idx >> 7; // qc 0..7
      const float4 v4 = *reinterpret_cast<const float4*>(
          state + (size_t)(b0 + bl) * kD + kc * KK + qc * 4);
      stT[qc * 4 + 0][bl] = v4.x;
      stT[qc * 4 + 1][bl] = v4.y;
      stT[qc * 4 + 2][bl] = v4.z;
      stT[qc * 4 + 3][bl] = v4.w;
      float4 a4 = {0.f, 0.f, 0.f, 0.f};
      if (v0 + bl < kV)
        a4 = *reinterpret_cast<const float4*>(
            sigs + (size_t)(v0 + bl) * kD + kc * KK + qc * 4);
      atT[qc * 4 + 0][bl] = a4.x;
      atT[qc * 4 + 1][bl] = a4.y;
      atT[qc * 4 + 2][bl] = a4.z;
      atT[qc * 4 + 3][bl] = a4.w;
    }
    __syncthreads();
#pragma unroll
    for (int kk = 0; kk < KK; ++kk) {
      const float4 sA = *reinterpret_cast<const float4*>(&stT[kk][ty * 8]);
      const float4 sB = *reinterpret_cast<const float4*>(&stT[kk][ty * 8 + 4]);
      const float4 aA = *reinterpret_cast<const float4*>(&atT[kk][tx * 4]);
      const float4 aB = *reinterpret_cast<const float4*>(&atT[kk][64 + tx * 4]);
      const float sb[8] = {sA.x, sA.y, sA.z, sA.w, sB.x, sB.y, sB.z, sB.w};
      const float av[8] = {aA.x, aA.y, aA.z, aA.w, aB.x, aB.y, aB.z, aB.w};
#pragma unroll
      for (int bi = 0; bi < 8; ++bi)
#pragma unroll
        for (int vi = 0; vi < 8; ++vi)
          acc[bi][vi] = fmaf(sb[bi], av[vi], acc[bi][vi]);
    }
  }

  const float x  = traw[0];
  const float sp = log1pf(expf(x));
  const float rt = 1.0f / fmaxf(sp, 1e-6f);

  float ssq_b[8], asq_v[8];
#pragma unroll
  for (int bi = 0; bi < 8; ++bi) ssq_b[bi] = ssq[b0 + ty * 8 + bi];
#pragma unroll
  for (int vi = 0; vi < 8; ++vi) {
    const int v = v0 + (vi < 4 ? tx * 4 + vi : 64 + tx * 4 + (vi - 4));
    asq_v[vi] = (v < kV) ? asq[v] : 0.0f;
  }

  if (v0 + LV <= kV) {                    // fast path: full tile, float4 stores
#pragma unroll
    for (int bi = 0; bi < 8; ++bi) {
      const int b = b0 + ty * 8 + bi;
      float4 o0, o1;
      float* p0 = &o0.x; float* p1 = &o1.x;
#pragma unroll
      for (int vi = 0; vi < 4; ++vi) {
        const float sq0 = ssq_b[bi] + asq_v[vi] - 2.0f * acc[bi][vi];
        p0[vi] = -sqrtf(fmaxf(sq0, 0.0f)) * rt;
        const float sq1 = ssq_b[bi] + asq_v[vi + 4] - 2.0f * acc[bi][vi + 4];
        p1[vi] = -sqrtf(fmaxf(sq1, 0.0f)) * rt;
      }
      *reinterpret_cast<float4*>(out + (size_t)b * kV + v0 + tx * 4) = o0;
      *reinterpret_cast<float4*>(out + (size_t)b * kV + v0 + 64 + tx * 4) = o1;
    }
  } else {                                // edge block: guarded scalar stores
#pragma unroll
    for (int bi = 0; bi < 8; ++bi) {
      const int b = b0 + ty * 8 + bi;
#pragma unroll
      for (int vi = 0; vi < 8; ++vi) {
        const int v = v0 + (vi < 4 ? tx * 4 + vi : 64 + tx * 4 + (vi - 4));
        if (v < kV) {
          const float sq = ssq_b[bi] + asq_v[vi] - 2.0f * acc[bi][vi];
          out[(size_t)b * kV + v] = -sqrtf(fmaxf(sq, 0.0f)) * rt;
        }
      }
    }
  }
}

// ---------------------------------------------------------------------------
extern "C" void kernel_launch(void* const* d_in, const int* in_sizes, int n_in,
                              void* d_out, int out_size, void* d_ws, size_t ws_size,
                              hipStream_t stream) {
  const int*   ids  = (const int*)d_in[0];     // [256,32]
  const float* emb  = (const float*)d_in[1];   // [50257,512]
  const float* dif  = (const float*)d_in[2];   // [512,512]
  const float* traw = (const float*)d_in[3];   // [1]
  float* out = (float*)d_out;                  // [256,50257]

  char* ws = (char*)d_ws;
  size_t off = 0;
  float*        all_sigs = (float*)(ws + off);        off += (size_t)kV * kD * sizeof(float);
  unsigned int* w2       = (unsigned int*)(ws + off); off += (size_t)kD * kD / 2 * sizeof(unsigned int);
  float*        state    = (float*)(ws + off);        off += (size_t)kB * kD * sizeof(float);
  float*        ssq      = (float*)(ws + off);        off += (size_t)256 * sizeof(float);
  float*        asq      = (float*)(ws + off);        off += (size_t)kV * sizeof(float);

  hipLaunchKernelGGL(k_signals, dim3(kV), dim3(128), 0, stream, emb, all_sigs, asq);
  hipLaunchKernelGGL(k_wprep, dim3(kD * kD / 2 / 256), dim3(256), 0, stream, dif, w2);
  hipLaunchKernelGGL(k_scan, dim3(SCAN_BLOCKS), dim3(512), 0, stream,
                     ids, all_sigs, (const uint4*)w2, state, ssq);
  const int vblocks = (kV + LV - 1) / LV;      // 393
  hipLaunchKernelGGL(k_logits, dim3(vblocks * 2), dim3(256), 0, stream,
                     state, ssq, all_sigs, asq, traw, out);
}

// Round 5
// 8972.565 us; speedup vs baseline: 1.0584x; 1.0584x over previous
//
#include <hip/hip_runtime.h>

// ---------------------------------------------------------------------------
// TorchAttractorLanguageModel. Round-4 post-mortem: WRITE_SIZE=8.1GB =
// scratch spill of the prefetch windows (launch_bounds(512) default capped
// VGPR at 128). Round 5: identical structure, but __launch_bounds__(512,2)
// (256-VGPR cap, no spill) + LDS pad to force 1 block/CU. This round also
// measures the true per-CU L2 W-pull ceiling (512KB/step/CU).
// ---------------------------------------------------------------------------

static constexpr int   kB     = 256;
static constexpr int   kT     = 32;
static constexpr int   kV     = 50257;
static constexpr int   kD     = 512;
static constexpr int   kSteps = 30;
static constexpr float kDT    = 0.04f;
static constexpr float kCubic = 0.008f;
static constexpr float kEpsLN = 1e-5f;

static constexpr int RR          = 2;     // state rows per scan block
static constexpr int SCAN_BLOCKS = kB / RR;   // 128

typedef _Float16 half1;
typedef _Float16 half2v __attribute__((ext_vector_type(2)));
union HU { unsigned int u; half2v h; half1 s[2]; unsigned short us[2]; };

#if defined(__has_builtin)
#if __has_builtin(__builtin_amdgcn_fdot2)
#define HAS_FDOT2 1
#endif
#endif

__device__ __forceinline__ float dot2acc(unsigned int a, unsigned int b, float c) {
  HU ua; ua.u = a;
  HU ub; ub.u = b;
#ifdef HAS_FDOT2
  return __builtin_amdgcn_fdot2(ua.h, ub.h, c, false);
#else
  c = fmaf((float)ua.s[0], (float)ub.s[0], c);
  return fmaf((float)ua.s[1], (float)ub.s[1], c);
#endif
}

// ---------------------------------------------------------------------------
// K1: all_sigs[v] = L2normalize(LayerNorm(emb[v])); asq[v] = ||sig_v||^2.
__global__ __launch_bounds__(128)
void k_signals(const float* __restrict__ emb, float* __restrict__ sigs,
               float* __restrict__ asq) {
  const int row = blockIdx.x;
  const int tid = threadIdx.x;
  const float4 x = reinterpret_cast<const float4*>(emb + (size_t)row * kD)[tid];
  float s = x.x + x.y + x.z + x.w;
  float q = x.x * x.x + x.y * x.y + x.z * x.z + x.w * x.w;
#pragma unroll
  for (int o = 32; o > 0; o >>= 1) {
    s += __shfl_xor(s, o);
    q += __shfl_xor(q, o);
  }
  __shared__ float ls[2], lq[2];
  const int wid = tid >> 6;
  if ((tid & 63) == 0) { ls[wid] = s; lq[wid] = q; }
  __syncthreads();
  s = ls[0] + ls[1];
  q = lq[0] + lq[1];
  const float mu   = s * (1.0f / kD);
  const float var  = fmaxf(q * (1.0f / kD) - mu * mu, 0.0f);
  const float rstd = rsqrtf(var + kEpsLN);
  const float n     = rstd * sqrtf((float)kD * var);
  const float scale = rstd / fmaxf(n, 1e-12f);
  float4 y;
  y.x = (x.x - mu) * scale;
  y.y = (x.y - mu) * scale;
  y.z = (x.z - mu) * scale;
  y.w = (x.w - mu) * scale;
  reinterpret_cast<float4*>(sigs + (size_t)row * kD)[tid] = y;
  if (tid == 0) asq[row] = scale * scale * (float)kD * var;
}

// ---------------------------------------------------------------------------
// K2: pack W to f16 in the wave-k-split layout. uint4 index:
//   ((w*8 + p)*8 + i)*64 + l   holds W[j = l+64i][k = 64w+8p .. +8)
__global__ __launch_bounds__(256)
void k_wprep(const float* __restrict__ dif, unsigned int* __restrict__ w2) {
  const int d = blockIdx.x * 256 + threadIdx.x;   // dword index, 131072 total
  const int qq = d & 3;
  const int u4 = d >> 2;
  const int l = u4 & 63;
  const int i = (u4 >> 6) & 7;
  const int p = (u4 >> 9) & 7;
  const int w = u4 >> 12;
  const int j = l + 64 * i;
  const int k = 64 * w + 8 * p + 2 * qq;
  HU u;
  u.s[0] = (half1)dif[(size_t)j * kD + k];
  u.s[1] = (half1)dif[(size_t)j * kD + k + 1];
  w2[d] = u.u;
}

// ---------------------------------------------------------------------------
__device__ __forceinline__ void comp8(const uint4 (&wv)[8], uint4 sv0, uint4 sv1,
                                      float (&acc)[RR][8]) {
#pragma unroll
  for (int i = 0; i < 8; ++i) {
    float a0 = acc[0][i];
    a0 = dot2acc(wv[i].x, sv0.x, a0);
    a0 = dot2acc(wv[i].y, sv0.y, a0);
    a0 = dot2acc(wv[i].z, sv0.z, a0);
    a0 = dot2acc(wv[i].w, sv0.w, a0);
    acc[0][i] = a0;
    float a1 = acc[1][i];
    a1 = dot2acc(wv[i].x, sv1.x, a1);
    a1 = dot2acc(wv[i].y, sv1.y, a1);
    a1 = dot2acc(wv[i].z, sv1.z, a1);
    a1 = dot2acc(wv[i].w, sv1.w, a1);
    acc[1][i] = a1;
  }
}

// K3: the scan. Wave w = k-slice [64w,64w+64); lane l accumulates partial y
// for j=l+64i. Partials reduced through red2 (pad-516, conflict-free).
// __launch_bounds__(512,2): 256-VGPR cap so the 2x8-uint4 prefetch windows
// stay in registers (round-4 spill fix). lds_pad forces 1 block/CU.
__global__ __launch_bounds__(512, 2)
void k_scan(const int* __restrict__ ids, const float* __restrict__ sigs,
            const uint4* __restrict__ w2, float* __restrict__ state,
            float* __restrict__ ssq) {
  const int tid  = threadIdx.x;
  const int lane = tid & 63;
  const int w    = tid >> 6;           // wave id == k-slice id
  const int b0   = blockIdx.x * RR;

  __shared__ unsigned short s_h[RR][kD];   // f16 state (2 KB)
  __shared__ float red[RR][8];             // mean partials
  __shared__ float red2[RR][8][516];       // GEMM partials (33 KB, padded)
  __shared__ float lds_pad[13000];         // 52 KB: total ~88 KB -> 1 block/CU
  if (ids[0] == (-2147483647 - 1)) {       // never true; keeps lds_pad alive
    lds_pad[tid] = (float)tid;
    state[0] = lds_pad[tid ^ 1];
  }

  float s_reg[RR], sig[RR];
#pragma unroll
  for (int r = 0; r < RR; ++r) {
    s_reg[r] = 0.0f;
    s_h[r][tid] = 0;
    if (lane == 0) red[r][w] = 0.0f;
  }

  const uint4* __restrict__ wp = w2 + (w << 12) + lane;
  uint4 wA[8], wB[8];
#pragma unroll
  for (int i = 0; i < 8; ++i) wA[i] = wp[(i << 6)];   // chunk 0 in flight

  __syncthreads();                       // prologue B1

  const uint4* sh0 = reinterpret_cast<const uint4*>(&s_h[0][0]);
  const uint4* sh1 = reinterpret_cast<const uint4*>(&s_h[1][0]);

  for (int t = 0; t < kT; ++t) {
#pragma unroll
    for (int r = 0; r < RR; ++r) {
      const int id = ids[(b0 + r) * kT + t];
      sig[r] = sigs[(size_t)id * kD + tid];
    }
    for (int step = 0; step < kSteps; ++step) {
      // --- mean of previous state (partials left in red before B1) ---
      float mean[RR];
#pragma unroll
      for (int r = 0; r < RR; ++r) {
        float m = 0.0f;
#pragma unroll
        for (int ww = 0; ww < 8; ++ww) m += red[r][ww];
        mean[r] = m * (1.0f / kD);
      }
      // --- wave-k-split GEMM, 8 chunks, 2-window prefetch ---
      float acc[RR][8];
#pragma unroll
      for (int r = 0; r < RR; ++r)
#pragma unroll
        for (int i = 0; i < 8; ++i) acc[r][i] = 0.0f;

#pragma unroll
      for (int ph = 0; ph < 4; ++ph) {
        const int pb = ph * 2 + 1, pn = (ph * 2 + 2) & 7;
#pragma unroll
        for (int i = 0; i < 8; ++i) wB[i] = wp[(pb << 9) + (i << 6)];
        {
          const uint4 sv0 = sh0[8 * w + ph * 2];
          const uint4 sv1 = sh1[8 * w + ph * 2];
          comp8(wA, sv0, sv1, acc);
        }
#pragma unroll
        for (int i = 0; i < 8; ++i) wA[i] = wp[(pn << 9) + (i << 6)];
        {
          const uint4 sv0 = sh0[8 * w + pb];
          const uint4 sv1 = sh1[8 * w + pb];
          comp8(wB, sv0, sv1, acc);
        }
      }
      // --- write partials (lanes consecutive -> conflict-free) ---
#pragma unroll
      for (int r = 0; r < RR; ++r)
#pragma unroll
        for (int i = 0; i < 8; ++i)
          red2[r][w][lane + (i << 6)] = acc[r][i];
      __syncthreads();                   // B2
      // --- reduce partials: thread t owns j=t ---
      float y[RR];
#pragma unroll
      for (int r = 0; r < RR; ++r) {
        float m = 0.0f;
#pragma unroll
        for (int ww = 0; ww < 8; ++ww) m += red2[r][ww][tid];
        y[r] = m;
      }
      // --- update + clip; stash f16 state + mean partials for next step ---
      float part[RR];
#pragma unroll
      for (int r = 0; r < RR; ++r) {
        const float cc    = s_reg[r] - mean[r];
        const float drift = y[r] + kCubic * cc * cc * cc + sig[r];
        float sn = fmaf(kDT, drift, s_reg[r]);
        sn = fminf(fmaxf(sn, -80.0f), 80.0f);
        s_reg[r] = sn;
        HU u; u.s[0] = (half1)sn; u.s[1] = (half1)0.0f;
        s_h[r][tid] = u.us[0];
        part[r] = sn;
      }
#pragma unroll
      for (int o = 32; o > 0; o >>= 1) {
#pragma unroll
        for (int r = 0; r < RR; ++r) part[r] += __shfl_xor(part[r], o);
      }
      if (lane == 0) {
#pragma unroll
        for (int r = 0; r < RR; ++r) red[r][w] = part[r];
      }
      __syncthreads();                   // B1
    }
  }

  // --- write state + per-row sum of squares ---
  float part[RR];
#pragma unroll
  for (int r = 0; r < RR; ++r) part[r] = s_reg[r] * s_reg[r];
#pragma unroll
  for (int o = 32; o > 0; o >>= 1) {
#pragma unroll
    for (int r = 0; r < RR; ++r) part[r] += __shfl_xor(part[r], o);
  }
  if (lane == 0) {
#pragma unroll
    for (int r = 0; r < RR; ++r) red[r][w] = part[r];
  }
#pragma unroll
  for (int r = 0; r < RR; ++r)
    state[(size_t)(b0 + r) * kD + tid] = s_reg[r];
  __syncthreads();
  if (tid < RR) {
    float m = 0.0f;
#pragma unroll
    for (int ww = 0; ww < 8; ++ww) m += red[tid][ww];
    ssq[b0 + tid] = m;
  }
}

// ---------------------------------------------------------------------------
// K4: logits = -sqrt(max(ssq_b + asq_v - 2*s.a, 0))/temp. 128x128 tile,
// 8x8 register micro-tile. (Round-4 version: total non-scan ~290us.)
static constexpr int LB = 128, LV = 128, KK = 32;

__global__ __launch_bounds__(256)
void k_logits(const float* __restrict__ state, const float* __restrict__ ssq,
              const float* __restrict__ sigs, const float* __restrict__ asq,
              const float* __restrict__ traw, float* __restrict__ out) {
  const int tid = threadIdx.x;
  const int vb = blockIdx.x >> 1, bb = blockIdx.x & 1;
  const int v0 = vb * LV, b0 = bb * LB;
  __shared__ float stT[KK][LB];   // 16 KB
  __shared__ float atT[KK][LV];   // 16 KB
  const int tx = tid & 15;
  const int ty = tid >> 4;

  float acc[8][8];
#pragma unroll
  for (int bi = 0; bi < 8; ++bi)
#pragma unroll
    for (int vi = 0; vi < 8; ++vi) acc[bi][vi] = 0.0f;

  for (int kc = 0; kc < kD / KK; ++kc) {
    __syncthreads();
#pragma unroll
    for (int it = 0; it < 4; ++it) {
      const int idx = tid + it * 256;          // 0..1023
      const int bl = idx & 127, qc = idx >> 7; // qc 0..7
      const float4 v4 = *reinterpret_cast<const float4*>(
          state + (size_t)(b0 + bl) * kD + kc * KK + qc * 4);
      stT[qc * 4 + 0][bl] = v4.x;
      stT[qc * 4 + 1][bl] = v4.y;
      stT[qc * 4 + 2][bl] = v4.z;
      stT[qc * 4 + 3][bl] = v4.w;
      float4 a4 = {0.f, 0.f, 0.f, 0.f};
      if (v0 + bl < kV)
        a4 = *reinterpret_cast<const float4*>(
            sigs + (size_t)(v0 + bl) * kD + kc * KK + qc * 4);
      atT[qc * 4 + 0][bl] = a4.x;
      atT[qc * 4 + 1][bl] = a4.y;
      atT[qc * 4 + 2][bl] = a4.z;
      atT[qc * 4 + 3][bl] = a4.w;
    }
    __syncthreads();
#pragma unroll
    for (int kk = 0; kk < KK; ++kk) {
      const float4 sA = *reinterpret_cast<const float4*>(&stT[kk][ty * 8]);
      const float4 sB = *reinterpret_cast<const float4*>(&stT[kk][ty * 8 + 4]);
      const float4 aA = *reinterpret_cast<const float4*>(&atT[kk][tx * 4]);
      const float4 aB = *reinterpret_cast<const float4*>(&atT[kk][64 + tx * 4]);
      const float sb[8] = {sA.x, sA.y, sA.z, sA.w, sB.x, sB.y, sB.z, sB.w};
      const float av[8] = {aA.x, aA.y, aA.z, aA.w, aB.x, aB.y, aB.z, aB.w};
#pragma unroll
      for (int bi = 0; bi < 8; ++bi)
#pragma unroll
        for (int vi = 0; vi < 8; ++vi)
          acc[bi][vi] = fmaf(sb[bi], av[vi], acc[bi][vi]);
    }
  }

  const float x  = traw[0];
  const float sp = log1pf(expf(x));
  const float rt = 1.0f / fmaxf(sp, 1e-6f);

  float ssq_b[8], asq_v[8];
#pragma unroll
  for (int bi = 0; bi < 8; ++bi) ssq_b[bi] = ssq[b0 + ty * 8 + bi];
#pragma unroll
  for (int vi = 0; vi < 8; ++vi) {
    const int v = v0 + (vi < 4 ? tx * 4 + vi : 64 + tx * 4 + (vi - 4));
    asq_v[vi] = (v < kV) ? asq[v] : 0.0f;
  }

  if (v0 + LV <= kV) {
#pragma unroll
    for (int bi = 0; bi < 8; ++bi) {
      const int b = b0 + ty * 8 + bi;
      float4 o0, o1;
      float* p0 = &o0.x; float* p1 = &o1.x;
#pragma unroll
      for (int vi = 0; vi < 4; ++vi) {
        const float sq0 = ssq_b[bi] + asq_v[vi] - 2.0f * acc[bi][vi];
        p0[vi] = -sqrtf(fmaxf(sq0, 0.0f)) * rt;
        const float sq1 = ssq_b[bi] + asq_v[vi + 4] - 2.0f * acc[bi][vi + 4];
        p1[vi] = -sqrtf(fmaxf(sq1, 0.0f)) * rt;
      }
      *reinterpret_cast<float4*>(out + (size_t)b * kV + v0 + tx * 4) = o0;
      *reinterpret_cast<float4*>(out + (size_t)b * kV + v0 + 64 + tx * 4) = o1;
    }
  } else {
#pragma unroll
    for (int bi = 0; bi < 8; ++bi) {
      const int b = b0 + ty * 8 + bi;
#pragma unroll
      for (int vi = 0; vi < 8; ++vi) {
        const int v = v0 + (vi < 4 ? tx * 4 + vi : 64 + tx * 4 + (vi - 4));
        if (v < kV) {
          const float sq = ssq_b[bi] + asq_v[vi] - 2.0f * acc[bi][vi];
          out[(size_t)b * kV + v] = -sqrtf(fmaxf(sq, 0.0f)) * rt;
        }
      }
    }
  }
}

// ---------------------------------------------------------------------------
extern "C" void kernel_launch(void* const* d_in, const int* in_sizes, int n_in,
                              void* d_out, int out_size, void* d_ws, size_t ws_size,
                              hipStream_t stream) {
  const int*   ids  = (const int*)d_in[0];     // [256,32]
  const float* emb  = (const float*)d_in[1];   // [50257,512]
  const float* dif  = (const float*)d_in[2];   // [512,512]
  const float* traw = (const float*)d_in[3];   // [1]
  float* out = (float*)d_out;                  // [256,50257]

  char* ws = (char*)d_ws;
  size_t off = 0;
  float*        all_sigs = (float*)(ws + off);        off += (size_t)kV * kD * sizeof(float);
  unsigned int* w2       = (unsigned int*)(ws + off); off += (size_t)kD * kD / 2 * sizeof(unsigned int);
  float*        state    = (float*)(ws + off);        off += (size_t)kB * kD * sizeof(float);
  float*        ssq      = (float*)(ws + off);        off += (size_t)256 * sizeof(float);
  float*        asq      = (float*)(ws + off);        off += (size_t)kV * sizeof(float);

  hipLaunchKernelGGL(k_signals, dim3(kV), dim3(128), 0, stream, emb, all_sigs, asq);
  hipLaunchKernelGGL(k_wprep, dim3(kD * kD / 2 / 256), dim3(256), 0, stream, dif, w2);
  hipLaunchKernelGGL(k_scan, dim3(SCAN_BLOCKS), dim3(512), 0, stream,
                     ids, all_sigs, (const uint4*)w2, state, ssq);
  const int vblocks = (kV + LV - 1) / LV;      // 393
  hipLaunchKernelGGL(k_logits, dim3(vblocks * 2), dim3(256), 0, stream,
                     state, ssq, all_sigs, asq, traw, out);
}

// Round 6
// 8964.513 us; speedup vs baseline: 1.0593x; 1.0009x over previous
//
#include <hip/hip_runtime.h>

// ---------------------------------------------------------------------------
// TorchAttractorLanguageModel. Round-5 post-mortem: VGPR cap stayed 128 —
// hipcc treated __launch_bounds__(512,2) as 2 BLOCKS/CU (16 waves/CU = 4/SIMD
// -> 512/4 = 128 cap) and the prefetch windows kept spilling (WRITE_SIZE
// 6.7GB). Round 6: __launch_bounds__(512,1) -> 1 block/CU -> 2 waves/SIMD ->
// 256-VGPR cap under either arg semantics. Everything else unchanged.
// ---------------------------------------------------------------------------

static constexpr int   kB     = 256;
static constexpr int   kT     = 32;
static constexpr int   kV     = 50257;
static constexpr int   kD     = 512;
static constexpr int   kSteps = 30;
static constexpr float kDT    = 0.04f;
static constexpr float kCubic = 0.008f;
static constexpr float kEpsLN = 1e-5f;

static constexpr int RR          = 2;     // state rows per scan block
static constexpr int SCAN_BLOCKS = kB / RR;   // 128

typedef _Float16 half1;
typedef _Float16 half2v __attribute__((ext_vector_type(2)));
union HU { unsigned int u; half2v h; half1 s[2]; unsigned short us[2]; };

#if defined(__has_builtin)
#if __has_builtin(__builtin_amdgcn_fdot2)
#define HAS_FDOT2 1
#endif
#endif

__device__ __forceinline__ float dot2acc(unsigned int a, unsigned int b, float c) {
  HU ua; ua.u = a;
  HU ub; ub.u = b;
#ifdef HAS_FDOT2
  return __builtin_amdgcn_fdot2(ua.h, ub.h, c, false);
#else
  c = fmaf((float)ua.s[0], (float)ub.s[0], c);
  return fmaf((float)ua.s[1], (float)ub.s[1], c);
#endif
}

// ---------------------------------------------------------------------------
// K1: all_sigs[v] = L2normalize(LayerNorm(emb[v])); asq[v] = ||sig_v||^2.
__global__ __launch_bounds__(128)
void k_signals(const float* __restrict__ emb, float* __restrict__ sigs,
               float* __restrict__ asq) {
  const int row = blockIdx.x;
  const int tid = threadIdx.x;
  const float4 x = reinterpret_cast<const float4*>(emb + (size_t)row * kD)[tid];
  float s = x.x + x.y + x.z + x.w;
  float q = x.x * x.x + x.y * x.y + x.z * x.z + x.w * x.w;
#pragma unroll
  for (int o = 32; o > 0; o >>= 1) {
    s += __shfl_xor(s, o);
    q += __shfl_xor(q, o);
  }
  __shared__ float ls[2], lq[2];
  const int wid = tid >> 6;
  if ((tid & 63) == 0) { ls[wid] = s; lq[wid] = q; }
  __syncthreads();
  s = ls[0] + ls[1];
  q = lq[0] + lq[1];
  const float mu   = s * (1.0f / kD);
  const float var  = fmaxf(q * (1.0f / kD) - mu * mu, 0.0f);
  const float rstd = rsqrtf(var + kEpsLN);
  const float n     = rstd * sqrtf((float)kD * var);
  const float scale = rstd / fmaxf(n, 1e-12f);
  float4 y;
  y.x = (x.x - mu) * scale;
  y.y = (x.y - mu) * scale;
  y.z = (x.z - mu) * scale;
  y.w = (x.w - mu) * scale;
  reinterpret_cast<float4*>(sigs + (size_t)row * kD)[tid] = y;
  if (tid == 0) asq[row] = scale * scale * (float)kD * var;
}

// ---------------------------------------------------------------------------
// K2: pack W to f16 in the wave-k-split layout. uint4 index:
//   ((w*8 + p)*8 + i)*64 + l   holds W[j = l+64i][k = 64w+8p .. +8)
__global__ __launch_bounds__(256)
void k_wprep(const float* __restrict__ dif, unsigned int* __restrict__ w2) {
  const int d = blockIdx.x * 256 + threadIdx.x;   // dword index, 131072 total
  const int qq = d & 3;
  const int u4 = d >> 2;
  const int l = u4 & 63;
  const int i = (u4 >> 6) & 7;
  const int p = (u4 >> 9) & 7;
  const int w = u4 >> 12;
  const int j = l + 64 * i;
  const int k = 64 * w + 8 * p + 2 * qq;
  HU u;
  u.s[0] = (half1)dif[(size_t)j * kD + k];
  u.s[1] = (half1)dif[(size_t)j * kD + k + 1];
  w2[d] = u.u;
}

// ---------------------------------------------------------------------------
__device__ __forceinline__ void comp8(const uint4 (&wv)[8], uint4 sv0, uint4 sv1,
                                      float (&acc)[RR][8]) {
#pragma unroll
  for (int i = 0; i < 8; ++i) {
    float a0 = acc[0][i];
    a0 = dot2acc(wv[i].x, sv0.x, a0);
    a0 = dot2acc(wv[i].y, sv0.y, a0);
    a0 = dot2acc(wv[i].z, sv0.z, a0);
    a0 = dot2acc(wv[i].w, sv0.w, a0);
    acc[0][i] = a0;
    float a1 = acc[1][i];
    a1 = dot2acc(wv[i].x, sv1.x, a1);
    a1 = dot2acc(wv[i].y, sv1.y, a1);
    a1 = dot2acc(wv[i].z, sv1.z, a1);
    a1 = dot2acc(wv[i].w, sv1.w, a1);
    acc[1][i] = a1;
  }
}

// K3: the scan. Wave w = k-slice [64w,64w+64); lane l accumulates partial y
// for j=l+64i. Partials reduced through red2 (pad-516, conflict-free).
// __launch_bounds__(512,1): 1 block/CU -> 2 waves/SIMD -> 256-VGPR cap, so
// the 2x8-uint4 prefetch windows stay in registers. lds_pad keeps 1 block/CU.
__global__ __launch_bounds__(512, 1)
void k_scan(const int* __restrict__ ids, const float* __restrict__ sigs,
            const uint4* __restrict__ w2, float* __restrict__ state,
            float* __restrict__ ssq) {
  const int tid  = threadIdx.x;
  const int lane = tid & 63;
  const int w    = tid >> 6;           // wave id == k-slice id
  const int b0   = blockIdx.x * RR;

  __shared__ unsigned short s_h[RR][kD];   // f16 state (2 KB)
  __shared__ float red[RR][8];             // mean partials
  __shared__ float red2[RR][8][516];       // GEMM partials (33 KB, padded)
  __shared__ float lds_pad[13000];         // 52 KB: total ~88 KB -> 1 block/CU
  if (ids[0] == (-2147483647 - 1)) {       // never true; keeps lds_pad alive
    lds_pad[tid] = (float)tid;
    state[0] = lds_pad[tid ^ 1];
  }

  float s_reg[RR], sig[RR];
#pragma unroll
  for (int r = 0; r < RR; ++r) {
    s_reg[r] = 0.0f;
    s_h[r][tid] = 0;
    if (lane == 0) red[r][w] = 0.0f;
  }

  const uint4* __restrict__ wp = w2 + (w << 12) + lane;
  uint4 wA[8], wB[8];
#pragma unroll
  for (int i = 0; i < 8; ++i) wA[i] = wp[(i << 6)];   // chunk 0 in flight

  __syncthreads();                       // prologue B1

  const uint4* sh0 = reinterpret_cast<const uint4*>(&s_h[0][0]);
  const uint4* sh1 = reinterpret_cast<const uint4*>(&s_h[1][0]);

  for (int t = 0; t < kT; ++t) {
#pragma unroll
    for (int r = 0; r < RR; ++r) {
      const int id = ids[(b0 + r) * kT + t];
      sig[r] = sigs[(size_t)id * kD + tid];
    }
    for (int step = 0; step < kSteps; ++step) {
      // --- mean of previous state (partials left in red before B1) ---
      float mean[RR];
#pragma unroll
      for (int r = 0; r < RR; ++r) {
        float m = 0.0f;
#pragma unroll
        for (int ww = 0; ww < 8; ++ww) m += red[r][ww];
        mean[r] = m * (1.0f / kD);
      }
      // --- wave-k-split GEMM, 8 chunks, 2-window prefetch ---
      float acc[RR][8];
#pragma unroll
      for (int r = 0; r < RR; ++r)
#pragma unroll
        for (int i = 0; i < 8; ++i) acc[r][i] = 0.0f;

#pragma unroll
      for (int ph = 0; ph < 4; ++ph) {
        const int pb = ph * 2 + 1, pn = (ph * 2 + 2) & 7;
#pragma unroll
        for (int i = 0; i < 8; ++i) wB[i] = wp[(pb << 9) + (i << 6)];
        {
          const uint4 sv0 = sh0[8 * w + ph * 2];
          const uint4 sv1 = sh1[8 * w + ph * 2];
          comp8(wA, sv0, sv1, acc);
        }
#pragma unroll
        for (int i = 0; i < 8; ++i) wA[i] = wp[(pn << 9) + (i << 6)];
        {
          const uint4 sv0 = sh0[8 * w + pb];
          const uint4 sv1 = sh1[8 * w + pb];
          comp8(wB, sv0, sv1, acc);
        }
      }
      // --- write partials (lanes consecutive -> conflict-free) ---
#pragma unroll
      for (int r = 0; r < RR; ++r)
#pragma unroll
        for (int i = 0; i < 8; ++i)
          red2[r][w][lane + (i << 6)] = acc[r][i];
      __syncthreads();                   // B2
      // --- reduce partials: thread t owns j=t ---
      float y[RR];
#pragma unroll
      for (int r = 0; r < RR; ++r) {
        float m = 0.0f;
#pragma unroll
        for (int ww = 0; ww < 8; ++ww) m += red2[r][ww][tid];
        y[r] = m;
      }
      // --- update + clip; stash f16 state + mean partials for next step ---
      float part[RR];
#pragma unroll
      for (int r = 0; r < RR; ++r) {
        const float cc    = s_reg[r] - mean[r];
        const float drift = y[r] + kCubic * cc * cc * cc + sig[r];
        float sn = fmaf(kDT, drift, s_reg[r]);
        sn = fminf(fmaxf(sn, -80.0f), 80.0f);
        s_reg[r] = sn;
        HU u; u.s[0] = (half1)sn; u.s[1] = (half1)0.0f;
        s_h[r][tid] = u.us[0];
        part[r] = sn;
      }
#pragma unroll
      for (int o = 32; o > 0; o >>= 1) {
#pragma unroll
        for (int r = 0; r < RR; ++r) part[r] += __shfl_xor(part[r], o);
      }
      if (lane == 0) {
#pragma unroll
        for (int r = 0; r < RR; ++r) red[r][w] = part[r];
      }
      __syncthreads();                   // B1
    }
  }

  // --- write state + per-row sum of squares ---
  float part[RR];
#pragma unroll
  for (int r = 0; r < RR; ++r) part[r] = s_reg[r] * s_reg[r];
#pragma unroll
  for (int o = 32; o > 0; o >>= 1) {
#pragma unroll
    for (int r = 0; r < RR; ++r) part[r] += __shfl_xor(part[r], o);
  }
  if (lane == 0) {
#pragma unroll
    for (int r = 0; r < RR; ++r) red[r][w] = part[r];
  }
#pragma unroll
  for (int r = 0; r < RR; ++r)
    state[(size_t)(b0 + r) * kD + tid] = s_reg[r];
  __syncthreads();
  if (tid < RR) {
    float m = 0.0f;
#pragma unroll
    for (int ww = 0; ww < 8; ++ww) m += red[tid][ww];
    ssq[b0 + tid] = m;
  }
}

// ---------------------------------------------------------------------------
// K4: logits = -sqrt(max(ssq_b + asq_v - 2*s.a, 0))/temp. 128x128 tile,
// 8x8 register micro-tile.
static constexpr int LB = 128, LV = 128, KK = 32;

__global__ __launch_bounds__(256)
void k_logits(const float* __restrict__ state, const float* __restrict__ ssq,
              const float* __restrict__ sigs, const float* __restrict__ asq,
              const float* __restrict__ traw, float* __restrict__ out) {
  const int tid = threadIdx.x;
  const int vb = blockIdx.x >> 1, bb = blockIdx.x & 1;
  const int v0 = vb * LV, b0 = bb * LB;
  __shared__ float stT[KK][LB];   // 16 KB
  __shared__ float atT[KK][LV];   // 16 KB
  const int tx = tid & 15;
  const int ty = tid >> 4;

  float acc[8][8];
#pragma unroll
  for (int bi = 0; bi < 8; ++bi)
#pragma unroll
    for (int vi = 0; vi < 8; ++vi) acc[bi][vi] = 0.0f;

  for (int kc = 0; kc < kD / KK; ++kc) {
    __syncthreads();
#pragma unroll
    for (int it = 0; it < 4; ++it) {
      const int idx = tid + it * 256;          // 0..1023
      const int bl = idx & 127, qc = idx >> 7; // qc 0..7
      const float4 v4 = *reinterpret_cast<const float4*>(
          state + (size_t)(b0 + bl) * kD + kc * KK + qc * 4);
      stT[qc * 4 + 0][bl] = v4.x;
      stT[qc * 4 + 1][bl] = v4.y;
      stT[qc * 4 + 2][bl] = v4.z;
      stT[qc * 4 + 3][bl] = v4.w;
      float4 a4 = {0.f, 0.f, 0.f, 0.f};
      if (v0 + bl < kV)
        a4 = *reinterpret_cast<const float4*>(
            sigs + (size_t)(v0 + bl) * kD + kc * KK + qc * 4);
      atT[qc * 4 + 0][bl] = a4.x;
      atT[qc * 4 + 1][bl] = a4.y;
      atT[qc * 4 + 2][bl] = a4.z;
      atT[qc * 4 + 3][bl] = a4.w;
    }
    __syncthreads();
#pragma unroll
    for (int kk = 0; kk < KK; ++kk) {
      const float4 sA = *reinterpret_cast<const float4*>(&stT[kk][ty * 8]);
      const float4 sB = *reinterpret_cast<const float4*>(&stT[kk][ty * 8 + 4]);
      const float4 aA = *reinterpret_cast<const float4*>(&atT[kk][tx * 4]);
      const float4 aB = *reinterpret_cast<const float4*>(&atT[kk][64 + tx * 4]);
      const float sb[8] = {sA.x, sA.y, sA.z, sA.w, sB.x, sB.y, sB.z, sB.w};
      const float av[8] = {aA.x, aA.y, aA.z, aA.w, aB.x, aB.y, aB.z, aB.w};
#pragma unroll
      for (int bi = 0; bi < 8; ++bi)
#pragma unroll
        for (int vi = 0; vi < 8; ++vi)
          acc[bi][vi] = fmaf(sb[bi], av[vi], acc[bi][vi]);
    }
  }

  const float x  = traw[0];
  const float sp = log1pf(expf(x));
  const float rt = 1.0f / fmaxf(sp, 1e-6f);

  float ssq_b[8], asq_v[8];
#pragma unroll
  for (int bi = 0; bi < 8; ++bi) ssq_b[bi] = ssq[b0 + ty * 8 + bi];
#pragma unroll
  for (int vi = 0; vi < 8; ++vi) {
    const int v = v0 + (vi < 4 ? tx * 4 + vi : 64 + tx * 4 + (vi - 4));
    asq_v[vi] = (v < kV) ? asq[v] : 0.0f;
  }

  if (v0 + LV <= kV) {
#pragma unroll
    for (int bi = 0; bi < 8; ++bi) {
      const int b = b0 + ty * 8 + bi;
      float4 o0, o1;
      float* p0 = &o0.x; float* p1 = &o1.x;
#pragma unroll
      for (int vi = 0; vi < 4; ++vi) {
        const float sq0 = ssq_b[bi] + asq_v[vi] - 2.0f * acc[bi][vi];
        p0[vi] = -sqrtf(fmaxf(sq0, 0.0f)) * rt;
        const float sq1 = ssq_b[bi] + asq_v[vi + 4] - 2.0f * acc[bi][vi + 4];
        p1[vi] = -sqrtf(fmaxf(sq1, 0.0f)) * rt;
      }
      *reinterpret_cast<float4*>(out + (size_t)b * kV + v0 + tx * 4) = o0;
      *reinterpret_cast<float4*>(out + (size_t)b * kV + v0 + 64 + tx * 4) = o1;
    }
  } else {
#pragma unroll
    for (int bi = 0; bi < 8; ++bi) {
      const int b = b0 + ty * 8 + bi;
#pragma unroll
      for (int vi = 0; vi < 8; ++vi) {
        const int v = v0 + (vi < 4 ? tx * 4 + vi : 64 + tx * 4 + (vi - 4));
        if (v < kV) {
          const float sq = ssq_b[bi] + asq_v[vi] - 2.0f * acc[bi][vi];
          out[(size_t)b * kV + v] = -sqrtf(fmaxf(sq, 0.0f)) * rt;
        }
      }
    }
  }
}

// ---------------------------------------------------------------------------
extern "C" void kernel_launch(void* const* d_in, const int* in_sizes, int n_in,
                              void* d_out, int out_size, void* d_ws, size_t ws_size,
                              hipStream_t stream) {
  const int*   ids  = (const int*)d_in[0];     // [256,32]
  const float* emb  = (const float*)d_in[1];   // [50257,512]
  const float* dif  = (const float*)d_in[2];   // [512,512]
  const float* traw = (const float*)d_in[3];   // [1]
  float* out = (float*)d_out;                  // [256,50257]

  char* ws = (char*)d_ws;
  size_t off = 0;
  float*        all_sigs = (float*)(ws + off);        off += (size_t)kV * kD * sizeof(float);
  unsigned int* w2       = (unsigned int*)(ws + off); off += (size_t)kD * kD / 2 * sizeof(unsigned int);
  float*        state    = (float*)(ws + off);        off += (size_t)kB * kD * sizeof(float);
  float*        ssq      = (float*)(ws + off);        off += (size_t)256 * sizeof(float);
  float*        asq      = (float*)(ws + off);        off += (size_t)kV * sizeof(float);

  hipLaunchKernelGGL(k_signals, dim3(kV), dim3(128), 0, stream, emb, all_sigs, asq);
  hipLaunchKernelGGL(k_wprep, dim3(kD * kD / 2 / 256), dim3(256), 0, stream, dif, w2);
  hipLaunchKernelGGL(k_scan, dim3(SCAN_BLOCKS), dim3(512), 0, stream,
                     ids, all_sigs, (const uint4*)w2, state, ssq);
  const int vblocks = (kV + LV - 1) / LV;      // 393
  hipLaunchKernelGGL(k_logits, dim3(vblocks * 2), dim3(256), 0, stream,
                     state, ssq, all_sigs, asq, traw, out);
}